// Round 1
// baseline (464.134 us; speedup 1.0000x reference)
//
#include <hip/hip_runtime.h>

// Problem constants (from reference): B=64, TOPK=2, E=16, C=1024, K=4096
#define BB    64
#define TOPK  2
#define EE    16
#define CC    1024
#define KK    4096

constexpr int RPB    = 16;                 // weight rows per tile (4 per wave)
constexpr int P      = 16;                 // max (token,slot) pairs per group
constexpr int KS     = 8;                  // K-split (partial sums via atomics)
constexpr int KH     = KK / KS;            // floats per K-slice (=512)
constexpr int NW     = KH / 4 / 64;        // float4 windows per lane (=2)
constexpr int NCT    = 16;                 // row-tiles streamed per block
constexpr int CHUNKS = CC / (RPB * NCT);   // row-chunks per (e, ks) (=4)

typedef float v4f __attribute__((ext_vector_type(4)));

// ---------------------------------------------------------------------------
// Kernel 1: block 0 builds per-expert routing lists; other blocks initialize
//   out[b,c] = residual[b,c] + sum_s ew[b,s] * bias[idx[b,s], c]
// ---------------------------------------------------------------------------
__global__ __launch_bounds__(256) void route_init(
    const int* __restrict__ idx, const float* __restrict__ ew,
    const float* __restrict__ bias, const float* __restrict__ resid,
    float* __restrict__ out, int* __restrict__ cnt, int* __restrict__ lists)
{
    if (blockIdx.x == 0) {
        __shared__ int scnt[EE];
        if (threadIdx.x < EE) scnt[threadIdx.x] = 0;
        __syncthreads();
        if (threadIdx.x < BB * TOPK) {
            int e = idx[threadIdx.x];
            int pos = atomicAdd(&scnt[e], 1);
            lists[e * 128 + pos] = threadIdx.x;   // pair id = b*TOPK + slot
        }
        __syncthreads();
        if (threadIdx.x < EE) cnt[threadIdx.x] = scnt[threadIdx.x];
    } else {
        int i = (blockIdx.x - 1) * 256 + threadIdx.x;   // i in [0, B*C)
        int b = i >> 10;                                 // C = 1024
        int c = i & (CC - 1);
        float v = resid[i];
#pragma unroll
        for (int s = 0; s < TOPK; s++) {
            int e = idx[b * TOPK + s];
            v += ew[b * TOPK + s] * bias[e * CC + c];
        }
        out[i] = v;
    }
}

// ---------------------------------------------------------------------------
// Kernel 2: grid = E * CHUNKS * KS = 512 blocks (exactly 2/CU), 256 threads.
//
// Round-5 restructure: the previous one-shot-block version reached only
// ~10% of HBM BW — each block's {burst prefetch -> vmcnt(0) drain barrier ->
// short compute -> retire} phase left the memory system idle most of the
// time. New structure: persistent streaming blocks.
//   1. Stage this expert's act rows (one K-slice, <=16 x 2KB) into LDS ONCE.
//   2. ct-loop over NCT=16 row-tiles with a DOUBLE-BUFFERED register weight
//      prefetch (explicit wA/wB names -> static indexing, no scratch).
//      The hot loop has NO barriers: LDS is read-only, so the next tile's
//      8 nt dwordx4 loads stay in flight under the current tile's compute —
//      only fine-grained compiler vmcnt(N) waits, never a full drain.
//   3. Per-tile shfl reduction + one atomic per (row, pair) as before.
// KS=8 (NW=2) keeps wA+wB at 64 VGPRs so the double buffer fits under the
// 256-VGPR / 2-waves-per-SIMD cap with acc[4][16]. LDS = 32 KB.
// Weights still read exactly once; act gross traffic drops 16x.
// ---------------------------------------------------------------------------
__global__ __launch_bounds__(256, 2) void moe_mlp2(
    const float* __restrict__ act, const float* __restrict__ ew,
    const float* __restrict__ W, float* __restrict__ out,
    const int* __restrict__ cnt, const int* __restrict__ lists)
{
    __shared__ float sact[P][KH];   // 16 x 512 x 4B = 32 KB

    const int bid = blockIdx.x;
    const int e   = bid >> 5;                  // 32 blocks per expert
    const int n   = cnt[e];
    if (n == 0) return;
    const int chunk = (bid >> 3) & (CHUNKS - 1);
    const int ks    = bid & (KS - 1);
    const int lane  = threadIdx.x & 63;
    const int wave  = threadIdx.x >> 6;
    const int rowB  = chunk * (RPB * NCT);     // block's first weight row

    // v4f-typed base for this wave's rows (row stride = KK/4 v4f)
    const v4f* __restrict__ Wbase =
        (const v4f*)(W + (size_t)(e * CC + rowB + wave * 4) * KK + ks * KH);

    // --- prefetch one 16-row tile's wave-slice (8 nt dwordx4) into regs ---
    auto LOADW = [&](v4f (&w)[4][NW], int t) {
#pragma unroll
        for (int r = 0; r < 4; r++)
#pragma unroll
            for (int kw = 0; kw < NW; kw++)
                w[r][kw] = __builtin_nontemporal_load(
                    Wbase + (size_t)(t * RPB + r) * (KK / 4) + kw * 64 + lane);
    };

    // --- compute + reduce + atomic for one tile from a register buffer ---
    auto TILE = [&](const v4f (&w)[4][NW], int t, int np, int g) {
        float acc[4][P];
#pragma unroll
        for (int r = 0; r < 4; r++)
#pragma unroll
            for (int p = 0; p < P; p++) acc[r][p] = 0.f;

#pragma unroll
        for (int kw = 0; kw < NW; kw++) {
            const int fb = (kw * 64 + lane) * 4;   // float idx within slice
#pragma unroll
            for (int pc = 0; pc < P / 4; pc++) {
                if (pc * 4 < np) {                  // wave-uniform guard
#pragma unroll
                    for (int j = 0; j < 4; j++) {
                        const int p = pc * 4 + j;
                        const v4f a = *(const v4f*)&sact[p][fb];
#pragma unroll
                        for (int r = 0; r < 4; r++)
                            acc[r][p] += w[r][kw].x * a.x + w[r][kw].y * a.y +
                                         w[r][kw].z * a.z + w[r][kw].w * a.w;
                    }
                }
            }
        }

        const int row0 = rowB + t * RPB + wave * 4;
#pragma unroll
        for (int p = 0; p < P; p++) {
            if (p < np) {   // compile-time p => static acc indexing
                float v0 = acc[0][p], v1 = acc[1][p];
                float v2 = acc[2][p], v3 = acc[3][p];
#pragma unroll
                for (int off = 32; off > 0; off >>= 1) {
                    v0 += __shfl_down(v0, off, 64);
                    v1 += __shfl_down(v1, off, 64);
                    v2 += __shfl_down(v2, off, 64);
                    v3 += __shfl_down(v3, off, 64);
                }
                if (lane == 0) {
                    int pr = lists[e * 128 + g + p];
                    float wgt = ew[pr];
                    float* o = out + (pr >> 1) * CC + row0;
                    atomicAdd(o + 0, wgt * v0);
                    atomicAdd(o + 1, wgt * v1);
                    atomicAdd(o + 2, wgt * v2);
                    atomicAdd(o + 3, wgt * v3);
                }
            }
        }
    };

    for (int g = 0; g < n; g += P) {
        const int np = min(P, n - g);
        if (g) __syncthreads();   // prev group's compute done before re-stage

        // --- async global->LDS staging, ONCE per group of pairs.
        //     Half-row granularity: one wave instr covers 64 lanes x 16B =
        //     1024 B = 256 floats = KH/2. lds dest is wave-uniform (HW rule:
        //     base + lane*16); global src carries the per-lane offset. ---
        for (int h = wave; h < 2 * np; h += 4) {
            int pr = lists[e * 128 + g + (h >> 1)];
            const float* gsrc = act + (size_t)pr * KK + ks * KH
                              + (h & 1) * (KH / 2) + lane * 4;
            __builtin_amdgcn_global_load_lds(
                (const __attribute__((address_space(1))) void*)gsrc,
                (__attribute__((address_space(3))) void*)
                    &sact[h >> 1][(h & 1) * (KH / 2)],
                16, 0, 0);
        }
        __syncthreads();   // drains lds staging (one-time cost per block)

        // --- barrier-free streaming ct-loop, double-buffered weights.
        //     unroll 1: keeps body ~2 tiles of code (I-cache friendly);
        //     next tile's loads are always in flight under current compute ---
        v4f wA[4][NW], wB[4][NW];
        LOADW(wA, 0);
#pragma unroll 1
        for (int t = 0; t < NCT; t += 2) {
            LOADW(wB, t + 1);
            TILE(wA, t, np, g);
            if (t + 2 < NCT) LOADW(wA, t + 2);
            TILE(wB, t + 1, np, g);
        }
    }
}

extern "C" void kernel_launch(void* const* d_in, const int* in_sizes, int n_in,
                              void* d_out, int out_size, void* d_ws, size_t ws_size,
                              hipStream_t stream) {
    const float* act   = (const float*)d_in[0];   // [B, TOPK, K]
    const int*   idx   = (const int*)d_in[1];     // [B, TOPK]
    const float* ew    = (const float*)d_in[2];   // [B, TOPK]
    const float* W     = (const float*)d_in[3];   // [E, C, K]
    const float* bias  = (const float*)d_in[4];   // [E, C]
    const float* resid = (const float*)d_in[5];   // [B, C]
    float* out = (float*)d_out;

    int* cnt   = (int*)d_ws;          // 16 ints
    int* lists = (int*)d_ws + 64;     // 16 * 128 ints, 256B-aligned offset

    route_init<<<1 + (BB * CC) / 256, 256, 0, stream>>>(
        idx, ew, bias, resid, out, cnt, lists);
    moe_mlp2<<<EE * CHUNKS * KS, 256, 0, stream>>>(
        act, ew, W, out, cnt, lists);
}

// Round 2
// 367.741 us; speedup vs baseline: 1.2621x; 1.2621x over previous
//
#include <hip/hip_runtime.h>

// Problem constants (from reference): B=64, TOPK=2, E=16, C=1024, K=4096
#define BB    64
#define TOPK  2
#define EE    16
#define CC    1024
#define KK    4096

constexpr int RPB = 16;            // weight rows per block (4 per wave)
constexpr int P   = 16;            // max (token,slot) pairs per group
constexpr int KS  = 8;             // K-split (partial sums via atomics)
constexpr int KH  = KK / KS;       // floats per K-slice (=512)
constexpr int NW  = KH / 4 / 64;   // float4 windows per slice per lane (=2)

typedef float v4f __attribute__((ext_vector_type(4)));

// ---------------------------------------------------------------------------
// Kernel 1: block 0 builds per-expert routing lists; other blocks initialize
//   out[b,c] = residual[b,c] + sum_s ew[b,s] * bias[idx[b,s], c]
// ---------------------------------------------------------------------------
__global__ __launch_bounds__(256) void route_init(
    const int* __restrict__ idx, const float* __restrict__ ew,
    const float* __restrict__ bias, const float* __restrict__ resid,
    float* __restrict__ out, int* __restrict__ cnt, int* __restrict__ lists)
{
    if (blockIdx.x == 0) {
        __shared__ int scnt[EE];
        if (threadIdx.x < EE) scnt[threadIdx.x] = 0;
        __syncthreads();
        if (threadIdx.x < BB * TOPK) {
            int e = idx[threadIdx.x];
            int pos = atomicAdd(&scnt[e], 1);
            lists[e * 128 + pos] = threadIdx.x;   // pair id = b*TOPK + slot
        }
        __syncthreads();
        if (threadIdx.x < EE) cnt[threadIdx.x] = scnt[threadIdx.x];
    } else {
        int i = (blockIdx.x - 1) * 256 + threadIdx.x;   // i in [0, B*C)
        int b = i >> 10;                                 // C = 1024
        int c = i & (CC - 1);
        float v = resid[i];
#pragma unroll
        for (int s = 0; s < TOPK; s++) {
            int e = idx[b * TOPK + s];
            v += ew[b * TOPK + s] * bias[e * CC + c];
        }
        out[i] = v;
    }
}

// ---------------------------------------------------------------------------
// Kernel 2: grid = E * (C/RPB) * KS = 8192 one-shot blocks, 256 threads.
//
// Round-1 lessons (rocprof): 512 streaming blocks gave 13.9% occupancy and
// ~1 TB/s — latency-bound. Fixes:
//   * Back to many one-shot blocks: 8192 blocks, 32 KB LDS, VGPR<=128
//     (__launch_bounds__(256,4)) -> 4 resident blocks = 16 waves/CU; one
//     block's 8-load weight burst overlaps other blocks' compute.
//   * Butterfly epilogue: lane holds 64 partials (4 rows x 16 pairs);
//     6 value-halving exchange steps = 63 shfls total (vs 384 for the old
//     per-pair shfl trees), all compile-time register indices. Lane l ends
//     with the full sum for (pair=l>>2, row=l&3) -> 64 atomics/wave with
//     4-consecutive addresses.
// Weights still read exactly once, in registers before the single barrier.
// ---------------------------------------------------------------------------
__global__ __launch_bounds__(256, 4) void moe_mlp2(
    const float* __restrict__ act, const float* __restrict__ ew,
    const float* __restrict__ W, float* __restrict__ out,
    const int* __restrict__ cnt, const int* __restrict__ lists)
{
    __shared__ float sact[P][KH];   // 16 x 512 x 4B = 32 KB

    const int bid = blockIdx.x;
    const int e   = bid >> 9;                 // 512 blocks per expert
    const int n   = cnt[e];
    if (n == 0) return;
    const int ct   = (bid >> 3) & 63;         // 64 row-tiles
    const int ks   = bid & (KS - 1);          // 8 K-slices
    const int lane = threadIdx.x & 63;
    const int wave = threadIdx.x >> 6;
    const int row0 = ct * RPB + wave * 4;

    // --- weight slice prefetch: 8 nt dwordx4 per lane, issued back-to-back;
    //     drained by the staging barrier below (one-shot, so that's wanted) ---
    const v4f* __restrict__ Wb =
        (const v4f*)(W + (size_t)(e * CC + row0) * KK + ks * KH);
    v4f w[4][NW];
#pragma unroll
    for (int r = 0; r < 4; r++)
#pragma unroll
        for (int kw = 0; kw < NW; kw++)
            w[r][kw] = __builtin_nontemporal_load(
                Wb + (size_t)r * (KK / 4) + kw * 64 + lane);

    for (int g = 0; g < n; g += P) {
        const int np = min(P, n - g);
        if (g) __syncthreads();   // prev group's compute done before re-stage

        // --- async global->LDS staging. Half-row granularity: one wave
        //     instr = 64 lanes x 16B = 1 KB = KH/2 floats. lds dest is
        //     wave-uniform base + lane*16 (HW rule); per-lane offset lives
        //     in the global src address. ---
        for (int h = wave; h < 2 * np; h += 4) {
            int pr = lists[e * 128 + g + (h >> 1)];
            const float* gsrc = act + (size_t)pr * KK + ks * KH
                              + (h & 1) * (KH / 2) + lane * 4;
            __builtin_amdgcn_global_load_lds(
                (const __attribute__((address_space(1))) void*)gsrc,
                (__attribute__((address_space(3))) void*)
                    &sact[h >> 1][(h & 1) * (KH / 2)],
                16, 0, 0);
        }
        __syncthreads();   // drains staging AND weight prefetch

        // --- accumulate: val[(p<<2)|r] = lane's partial for (pair p, row r)
        float val[64];
#pragma unroll
        for (int i = 0; i < 64; i++) val[i] = 0.f;

#pragma unroll
        for (int kw = 0; kw < NW; kw++) {
            const int fb = (kw * 64 + lane) * 4;   // float idx within slice
#pragma unroll
            for (int pc = 0; pc < P / 4; pc++) {
                if (pc * 4 < np) {                  // wave-uniform guard
#pragma unroll
                    for (int j = 0; j < 4; j++) {
                        const int p = pc * 4 + j;
                        const v4f a = *(const v4f*)&sact[p][fb];
#pragma unroll
                        for (int r = 0; r < 4; r++)
                            val[(p << 2) | r] +=
                                w[r][kw].x * a.x + w[r][kw].y * a.y +
                                w[r][kw].z * a.z + w[r][kw].w * a.w;
                    }
                }
            }
        }

        // --- butterfly reduction, 63 shfls total. Invariant: after step s,
        //     slot i (i % 2^(s+1) == 0) holds the partial sum over the
        //     2^(s+1)-lane group of logical value (i | (lane & (2^(s+1)-1))).
        //     After 6 steps lane l's val[0] = full 64-lane sum of value l. ---
#pragma unroll
        for (int s = 0; s < 6; s++) {
            const int m = 1 << s;
            const bool hi = (lane & m) != 0;
#pragma unroll
            for (int i = 0; i < 64; i += 2 * m) {
                float send = hi ? val[i] : val[i + m];
                float recv = __shfl_xor(send, m, 64);
                val[i] = (hi ? val[i + m] : val[i]) + recv;
            }
        }

        // lane l owns (pair = l>>2, row = row0 + (l&3)); dead pairs (>=np)
        // hold garbage but never escape their own lanes in the butterfly.
        const int p = lane >> 2;
        if (p < np) {
            int pr = lists[e * 128 + g + p];
            atomicAdd(out + (size_t)(pr >> 1) * CC + row0 + (lane & 3),
                      ew[pr] * val[0]);
        }
    }
}

extern "C" void kernel_launch(void* const* d_in, const int* in_sizes, int n_in,
                              void* d_out, int out_size, void* d_ws, size_t ws_size,
                              hipStream_t stream) {
    const float* act   = (const float*)d_in[0];   // [B, TOPK, K]
    const int*   idx   = (const int*)d_in[1];     // [B, TOPK]
    const float* ew    = (const float*)d_in[2];   // [B, TOPK]
    const float* W     = (const float*)d_in[3];   // [E, C, K]
    const float* bias  = (const float*)d_in[4];   // [E, C]
    const float* resid = (const float*)d_in[5];   // [B, C]
    float* out = (float*)d_out;

    int* cnt   = (int*)d_ws;          // 16 ints
    int* lists = (int*)d_ws + 64;     // 16 * 128 ints, 256B-aligned offset

    route_init<<<1 + (BB * CC) / 256, 256, 0, stream>>>(
        idx, ew, bias, resid, out, cnt, lists);
    moe_mlp2<<<EE * (CC / RPB) * KS, 256, 0, stream>>>(
        act, ew, W, out, cnt, lists);
}